// Round 2
// baseline (3160.879 us; speedup 1.0000x reference)
//
#include <hip/hip_runtime.h>
#include <stdint.h>

#define D_MODEL 1024
#define N_HEADS 16
#define HEAD_DIM 64
#define BATCH 4
#define SEQ 2048
#define ROWS (BATCH * SEQ)   /* 8192 */
#define K3 (3 * D_MODEL)     /* 3072 */

typedef unsigned short u16;
typedef __attribute__((ext_vector_type(8))) short short8;
typedef __attribute__((ext_vector_type(4))) float floatx4;

__device__ __forceinline__ float bf2f(u16 u) {
    return __uint_as_float(((unsigned)u) << 16);
}
__device__ __forceinline__ u16 f2b(float f) {
    unsigned u = __float_as_uint(f);
    u = u + 0x7fffu + ((u >> 16) & 1u);   // RNE
    return (u16)(u >> 16);
}

// -------------------------------------------------- fp32 -> bf16 conversions
// x[n] fp32 -> xb[n] bf16
__global__ __launch_bounds__(256) void conv_f2b(const float* __restrict__ x,
                                                u16* __restrict__ xb, int n) {
    int i = blockIdx.x * 256 + threadIdx.x;
    if (i < n) xb[i] = f2b(x[i]);
}

// w[R][C] fp32 -> wt[C][R] bf16 (coalesced read)
__global__ __launch_bounds__(256) void transpose_f2b(const float* __restrict__ w,
                                                     u16* __restrict__ wt,
                                                     int R, int C) {
    int idx = blockIdx.x * 256 + threadIdx.x;
    if (idx >= R * C) return;
    int r = idx / C, c = idx - r * C;
    wt[(size_t)c * R + r] = f2b(w[idx]);
}

// ---------------------------------------------------------------- GEMM core
// C[M][N] = A[M][K] * B[K][N], A bf16 row-major, B given as Bt[N][K] bf16.
// 64x64 block tile, 256 threads = 4 waves in 2x2, BK=64, mfma 16x16x32 bf16.
// LDS rows padded to 72 elems (144 B -> 16B-aligned frag reads, 2-way-max
// bank aliasing which is free on gfx950).

#define GEMM_CORE(KDIM)                                                        \
    __shared__ u16 As[64][72];                                                 \
    __shared__ u16 Bs[64][72];                                                 \
    const int tid  = threadIdx.x;                                              \
    const int wave = tid >> 6, lane = tid & 63;                                \
    const int wr = wave >> 1, wc = wave & 1;                                   \
    const int m0 = blockIdx.y * 64, n0 = blockIdx.x * 64;                      \
    const int lr = tid >> 2, lc = (tid & 3) * 16;                              \
    const u16* Ap = A + (size_t)(m0 + lr) * (KDIM) + lc;                       \
    const u16* Bp = Bt + (size_t)(n0 + lr) * (KDIM) + lc;                      \
    floatx4 acc[2][2] = {};                                                    \
    for (int k0 = 0; k0 < (KDIM); k0 += 64) {                                  \
        uint4 a0 = *(const uint4*)(Ap + k0);                                   \
        uint4 a1 = *(const uint4*)(Ap + k0 + 8);                               \
        uint4 b0 = *(const uint4*)(Bp + k0);                                   \
        uint4 b1 = *(const uint4*)(Bp + k0 + 8);                               \
        __syncthreads();                                                       \
        *(uint4*)&As[lr][lc]     = a0;                                         \
        *(uint4*)&As[lr][lc + 8] = a1;                                         \
        *(uint4*)&Bs[lr][lc]     = b0;                                         \
        *(uint4*)&Bs[lr][lc + 8] = b1;                                         \
        __syncthreads();                                                       \
        _Pragma("unroll")                                                      \
        for (int ks = 0; ks < 2; ++ks) {                                       \
            const int kk = ks * 32 + (lane >> 4) * 8;                          \
            short8 af0 = *(const short8*)&As[wr * 32 + (lane & 15)][kk];       \
            short8 af1 = *(const short8*)&As[wr * 32 + 16 + (lane & 15)][kk];  \
            short8 bf0 = *(const short8*)&Bs[wc * 32 + (lane & 15)][kk];       \
            short8 bf1 = *(const short8*)&Bs[wc * 32 + 16 + (lane & 15)][kk];  \
            acc[0][0] = __builtin_amdgcn_mfma_f32_16x16x32_bf16(af0, bf0, acc[0][0], 0, 0, 0); \
            acc[0][1] = __builtin_amdgcn_mfma_f32_16x16x32_bf16(af0, bf1, acc[0][1], 0, 0, 0); \
            acc[1][0] = __builtin_amdgcn_mfma_f32_16x16x32_bf16(af1, bf0, acc[1][0], 0, 0, 0); \
            acc[1][1] = __builtin_amdgcn_mfma_f32_16x16x32_bf16(af1, bf1, acc[1][1], 0, 0, 0); \
        }                                                                      \
    }

// GEMM1: xb[8192][1024] @ wqkv -> scatter q/k/v as [B*H][T][64] bf16
__global__ __launch_bounds__(256) void gemm_qkv(const u16* __restrict__ A,
                                                const u16* __restrict__ Bt,
                                                u16* __restrict__ qo,
                                                u16* __restrict__ ko,
                                                u16* __restrict__ vo) {
    GEMM_CORE(D_MODEL)
    #pragma unroll
    for (int i = 0; i < 2; ++i)
        #pragma unroll
        for (int j = 0; j < 2; ++j) {
            const int col   = n0 + wc * 32 + j * 16 + (lane & 15);
            const int rb    = m0 + wr * 32 + i * 16 + (lane >> 4) * 4;
            const int which = col >> 10;
            const int cc    = col & 1023;
            const int h = cc >> 6, d = cc & 63;
            u16* dst = which == 0 ? qo : (which == 1 ? ko : vo);
            #pragma unroll
            for (int rr = 0; rr < 4; ++rr) {
                const int row = rb + rr;
                const int b = row >> 11, t = row & 2047;
                dst[(((size_t)(b * N_HEADS + h)) * SEQ + t) * HEAD_DIM + d] =
                    f2b(acc[i][j][rr]);
            }
        }
}

// GEMM2: attn_out[8192][1024] @ wproj + bias -> d_out fp32 row-major
__global__ __launch_bounds__(256) void gemm_proj(const u16* __restrict__ A,
                                                 const u16* __restrict__ Bt,
                                                 const float* __restrict__ bias,
                                                 float* __restrict__ out) {
    GEMM_CORE(D_MODEL)
    #pragma unroll
    for (int i = 0; i < 2; ++i)
        #pragma unroll
        for (int j = 0; j < 2; ++j) {
            const int col = n0 + wc * 32 + j * 16 + (lane & 15);
            const int rb  = m0 + wr * 32 + i * 16 + (lane >> 4) * 4;
            const float bv = bias[col];
            #pragma unroll
            for (int rr = 0; rr < 4; ++rr) {
                const int row = rb + rr;
                out[(size_t)row * D_MODEL + col] = acc[i][j][rr] + bv;
            }
        }
}

// ---------------------------------------------------------------- attention
// One wave per query row; online softmax over 64-key chunks.
// QK phase: lane = key index (q broadcast from LDS).
// PV phase: lane = head dim (p broadcast via shfl; v reads coalesced).
// Finite sentinel (-1e30) instead of -inf: no inf arithmetic anywhere.
__global__ __launch_bounds__(256) void attn(const u16* __restrict__ q,
                                            const u16* __restrict__ k,
                                            const u16* __restrict__ v,
                                            u16* __restrict__ o) {
    const int wave = threadIdx.x >> 6, lane = threadIdx.x & 63;
    const int t  = blockIdx.x * 4 + wave;
    const int bh = blockIdx.y;
    __shared__ float qs[4][64];
    const u16* qrow = q + ((size_t)bh * SEQ + t) * HEAD_DIM;
    qs[wave][lane] = bf2f(qrow[lane]) * 0.125f;   // 1/sqrt(64)
    __syncthreads();
    const float4* qv = (const float4*)qs[wave];
    const u16* kb = k + (size_t)bh * SEQ * HEAD_DIM;
    const u16* vb = v + (size_t)bh * SEQ * HEAD_DIM;
    const float SENT = -1e30f;
    float m = SENT, l = 0.f, acc = 0.f;
    const int nchunk = (t >> 6) + 1;
    for (int c = 0; c < nchunk; ++c) {
        const int kj = c * 64 + lane;
        float s = SENT;
        if (kj <= t) {
            const uint4* kr = (const uint4*)(kb + (size_t)kj * HEAD_DIM);
            float dot = 0.f;
            #pragma unroll
            for (int u2 = 0; u2 < 8; ++u2) {
                uint4  pk  = kr[u2];
                float4 q01 = qv[2 * u2];
                float4 q23 = qv[2 * u2 + 1];
                dot += q01.x * __uint_as_float(pk.x << 16);
                dot += q01.y * __uint_as_float(pk.x & 0xffff0000u);
                dot += q01.z * __uint_as_float(pk.y << 16);
                dot += q01.w * __uint_as_float(pk.y & 0xffff0000u);
                dot += q23.x * __uint_as_float(pk.z << 16);
                dot += q23.y * __uint_as_float(pk.z & 0xffff0000u);
                dot += q23.z * __uint_as_float(pk.w << 16);
                dot += q23.w * __uint_as_float(pk.w & 0xffff0000u);
            }
            s = dot;
        }
        // wave-wide max of scores
        float cm = s;
        #pragma unroll
        for (int off = 32; off; off >>= 1) cm = fmaxf(cm, __shfl_xor(cm, off));
        const float nm    = fmaxf(m, cm);          // finite: cm has >=1 valid lane
        const float p     = (kj <= t) ? __expf(s - nm) : 0.f;
        const float alpha = __expf(m - nm);        // first iter: exp(-1e30)=0
        float ps = p;
        #pragma unroll
        for (int off = 32; off; off >>= 1) ps += __shfl_xor(ps, off);
        l = l * alpha + ps;
        acc *= alpha;
        const u16* vr = vb + (size_t)c * 64 * HEAD_DIM + lane;
        #pragma unroll 8
        for (int j2 = 0; j2 < 64; ++j2)
            acc += __shfl(p, j2) * bf2f(vr[j2 * HEAD_DIM]);
        m = nm;
    }
    const int b = bh >> 4, h = bh & 15;
    o[((size_t)(b * SEQ + t)) * D_MODEL + h * HEAD_DIM + lane] = f2b(acc / l);
}

// ---------------------------------------------------------------- launch
extern "C" void kernel_launch(void* const* d_in, const int* in_sizes, int n_in,
                              void* d_out, int out_size, void* d_ws, size_t ws_size,
                              hipStream_t stream) {
    const float* x      = (const float*)d_in[0];
    const float* w_qkv  = (const float*)d_in[1];
    const float* w_proj = (const float*)d_in[2];
    const float* b_proj = (const float*)d_in[3];
    float* out = (float*)d_out;

    // workspace carve-up (bf16 elements): ~92.3 MB total
    u16* xb      = (u16*)d_ws;                                 // [8192][1024]
    u16* wt_qkv  = xb + (size_t)ROWS * D_MODEL;                // [3072][1024]
    u16* wt_proj = wt_qkv + (size_t)D_MODEL * K3;              // [1024][1024]
    u16* qws     = wt_proj + (size_t)D_MODEL * D_MODEL;        // [64][2048][64]
    u16* kws     = qws + (size_t)ROWS * D_MODEL;
    u16* vws     = kws + (size_t)ROWS * D_MODEL;
    u16* aout    = vws + (size_t)ROWS * D_MODEL;               // [8192][1024]

    conv_f2b<<<(ROWS * D_MODEL + 255) / 256, 256, 0, stream>>>(x, xb, ROWS * D_MODEL);
    transpose_f2b<<<(D_MODEL * K3 + 255) / 256, 256, 0, stream>>>(w_qkv, wt_qkv, D_MODEL, K3);
    transpose_f2b<<<(D_MODEL * D_MODEL + 255) / 256, 256, 0, stream>>>(w_proj, wt_proj, D_MODEL, D_MODEL);

    gemm_qkv<<<dim3(K3 / 64, ROWS / 64), 256, 0, stream>>>(xb, wt_qkv, qws, kws, vws);

    attn<<<dim3(SEQ / 4, BATCH * N_HEADS), 256, 0, stream>>>(qws, kws, vws, aout);

    gemm_proj<<<dim3(D_MODEL / 64, ROWS / 64), 256, 0, stream>>>(aout, wt_proj, b_proj, out);
}

// Round 3
// 697.477 us; speedup vs baseline: 4.5319x; 4.5319x over previous
//
#include <hip/hip_runtime.h>
#include <stdint.h>

#define D_MODEL 1024
#define N_HEADS 16
#define HEAD_DIM 64
#define BATCH 4
#define SEQ 2048
#define ROWS (BATCH * SEQ)   /* 8192 */
#define K3 (3 * D_MODEL)     /* 3072 */

typedef unsigned short u16;
typedef __attribute__((ext_vector_type(8))) short short8;
typedef __attribute__((ext_vector_type(4))) float floatx4;

__device__ __forceinline__ float bf2f(u16 u) {
    return __uint_as_float(((unsigned)u) << 16);
}
__device__ __forceinline__ u16 f2b(float f) {
    unsigned u = __float_as_uint(f);
    u = u + 0x7fffu + ((u >> 16) & 1u);   // RNE
    return (u16)(u >> 16);
}

// -------------------------------------------------- fp32 -> bf16 conversions
__global__ __launch_bounds__(256) void conv_f2b(const float* __restrict__ x,
                                                u16* __restrict__ xb, int n) {
    int i = blockIdx.x * 256 + threadIdx.x;
    if (i < n) xb[i] = f2b(x[i]);
}

// w[R][C] fp32 -> wt[C][R] bf16 (coalesced read)
__global__ __launch_bounds__(256) void transpose_f2b(const float* __restrict__ w,
                                                     u16* __restrict__ wt,
                                                     int R, int C) {
    int idx = blockIdx.x * 256 + threadIdx.x;
    if (idx >= R * C) return;
    int r = idx / C, c = idx - r * C;
    wt[(size_t)c * R + r] = f2b(w[idx]);
}

// ---------------------------------------------------------------- GEMM core
// (unchanged from passing round) 64x64 tile, 4 waves 2x2, BK=64, 16x16x32 bf16.
#define GEMM_CORE(KDIM)                                                        \
    __shared__ u16 As[64][72];                                                 \
    __shared__ u16 Bs[64][72];                                                 \
    const int tid  = threadIdx.x;                                              \
    const int wave = tid >> 6, lane = tid & 63;                                \
    const int wr = wave >> 1, wc = wave & 1;                                   \
    const int m0 = blockIdx.y * 64, n0 = blockIdx.x * 64;                      \
    const int lr = tid >> 2, lc = (tid & 3) * 16;                              \
    const u16* Ap = A + (size_t)(m0 + lr) * (KDIM) + lc;                       \
    const u16* Bp = Bt + (size_t)(n0 + lr) * (KDIM) + lc;                      \
    floatx4 acc[2][2] = {};                                                    \
    for (int k0 = 0; k0 < (KDIM); k0 += 64) {                                  \
        uint4 a0 = *(const uint4*)(Ap + k0);                                   \
        uint4 a1 = *(const uint4*)(Ap + k0 + 8);                               \
        uint4 b0 = *(const uint4*)(Bp + k0);                                   \
        uint4 b1 = *(const uint4*)(Bp + k0 + 8);                               \
        __syncthreads();                                                       \
        *(uint4*)&As[lr][lc]     = a0;                                         \
        *(uint4*)&As[lr][lc + 8] = a1;                                         \
        *(uint4*)&Bs[lr][lc]     = b0;                                         \
        *(uint4*)&Bs[lr][lc + 8] = b1;                                         \
        __syncthreads();                                                       \
        _Pragma("unroll")                                                      \
        for (int ks = 0; ks < 2; ++ks) {                                       \
            const int kk = ks * 32 + (lane >> 4) * 8;                          \
            short8 af0 = *(const short8*)&As[wr * 32 + (lane & 15)][kk];       \
            short8 af1 = *(const short8*)&As[wr * 32 + 16 + (lane & 15)][kk];  \
            short8 bf0 = *(const short8*)&Bs[wc * 32 + (lane & 15)][kk];       \
            short8 bf1 = *(const short8*)&Bs[wc * 32 + 16 + (lane & 15)][kk];  \
            acc[0][0] = __builtin_amdgcn_mfma_f32_16x16x32_bf16(af0, bf0, acc[0][0], 0, 0, 0); \
            acc[0][1] = __builtin_amdgcn_mfma_f32_16x16x32_bf16(af0, bf1, acc[0][1], 0, 0, 0); \
            acc[1][0] = __builtin_amdgcn_mfma_f32_16x16x32_bf16(af1, bf0, acc[1][0], 0, 0, 0); \
            acc[1][1] = __builtin_amdgcn_mfma_f32_16x16x32_bf16(af1, bf1, acc[1][1], 0, 0, 0); \
        }                                                                      \
    }

// GEMM1: xb @ wqkv -> q,k as [BH][T][64]; v TRANSPOSED as [BH][64][T]
__global__ __launch_bounds__(256) void gemm_qkv(const u16* __restrict__ A,
                                                const u16* __restrict__ Bt,
                                                u16* __restrict__ qo,
                                                u16* __restrict__ ko,
                                                u16* __restrict__ vo) {
    GEMM_CORE(D_MODEL)
    #pragma unroll
    for (int i = 0; i < 2; ++i)
        #pragma unroll
        for (int j = 0; j < 2; ++j) {
            const int col   = n0 + wc * 32 + j * 16 + (lane & 15);
            const int rb    = m0 + wr * 32 + i * 16 + (lane >> 4) * 4;
            const int which = col >> 10;
            const int cc    = col & 1023;
            const int h = cc >> 6, d = cc & 63;
            #pragma unroll
            for (int rr = 0; rr < 4; ++rr) {
                const int row = rb + rr;
                const int b = row >> 11, t = row & 2047;
                const u16 val = f2b(acc[i][j][rr]);
                if (which == 0)
                    qo[(((size_t)(b * N_HEADS + h)) * SEQ + t) * HEAD_DIM + d] = val;
                else if (which == 1)
                    ko[(((size_t)(b * N_HEADS + h)) * SEQ + t) * HEAD_DIM + d] = val;
                else
                    vo[(((size_t)(b * N_HEADS + h)) * HEAD_DIM + d) * SEQ + t] = val;
            }
        }
}

// GEMM2: attn_out[8192][1024] @ wproj + bias -> d_out fp32 row-major
__global__ __launch_bounds__(256) void gemm_proj(const u16* __restrict__ A,
                                                 const u16* __restrict__ Bt,
                                                 const float* __restrict__ bias,
                                                 float* __restrict__ out) {
    GEMM_CORE(D_MODEL)
    #pragma unroll
    for (int i = 0; i < 2; ++i)
        #pragma unroll
        for (int j = 0; j < 2; ++j) {
            const int col = n0 + wc * 32 + j * 16 + (lane & 15);
            const int rb  = m0 + wr * 32 + i * 16 + (lane >> 4) * 4;
            const float bv = bias[col];
            #pragma unroll
            for (int rr = 0; rr < 4; ++rr) {
                const int row = rb + rr;
                out[(size_t)row * D_MODEL + col] = acc[i][j][rr] + bv;
            }
        }
}

// ------------------------------------------------------- MFMA flash attention
// Block = 64 queries (4 waves x 16), grid (32 qt, 64 bh). Per wave:
// online-softmax over 64-key chunks. QK: mfma C-layout rows=query -> row
// reductions are shfl_xor {1,2,4,8}. P goes C-layout -> A-layout via a
// per-wave LDS tile (pad 72: 2-way bank alias max = free). PV reads
// Vt[bh][d][T] so B-frags are contiguous 16B. Causal: wave w does tiles
// 0..w of the diagonal chunk, triangular mask on tile w. No __syncthreads.
__global__ __launch_bounds__(256) void attn_mfma(const u16* __restrict__ q,
                                                 const u16* __restrict__ k,
                                                 const u16* __restrict__ vt,
                                                 u16* __restrict__ o) {
    __shared__ u16 Plds[4][16][72];
    const int tid = threadIdx.x;
    const int w = tid >> 6, lane = tid & 63;
    const int quad = lane >> 4, l15 = lane & 15;
    const int qt = (int)gridDim.x - 1 - (int)blockIdx.x;   // longest blocks first
    const int bh = blockIdx.y;

    const int qrow = qt * 64 + w * 16 + l15;               // A-frag m index
    const u16* qp = q + ((size_t)bh * SEQ + qrow) * HEAD_DIM + quad * 8;
    const short8 aq0 = *(const short8*)(qp);
    const short8 aq1 = *(const short8*)(qp + 32);
    const u16* kb  = k  + (size_t)bh * SEQ * HEAD_DIM;
    const u16* vtb = vt + (size_t)bh * HEAD_DIM * SEQ;

    floatx4 O[4] = {};
    float mr[4] = {-1e30f, -1e30f, -1e30f, -1e30f};
    float lr[4] = {0.f, 0.f, 0.f, 0.f};

    for (int c = 0; c <= qt; ++c) {
        const int ntiles = (c == qt) ? (w + 1) : 4;        // wave-uniform
        const int nhalf  = (ntiles <= 2) ? 1 : 2;
        // ---- QK^T: S[t] = Q(16x64) . K_tile^T(64x16)
        floatx4 s[4] = {};
        #pragma unroll
        for (int t = 0; t < 4; ++t) {
            if (t < ntiles) {
                const u16* kp = kb + ((size_t)(c * 64 + t * 16 + l15)) * HEAD_DIM + quad * 8;
                short8 bk0 = *(const short8*)kp;
                short8 bk1 = *(const short8*)(kp + 32);
                floatx4 z = {};
                z = __builtin_amdgcn_mfma_f32_16x16x32_bf16(aq0, bk0, z, 0, 0, 0);
                z = __builtin_amdgcn_mfma_f32_16x16x32_bf16(aq1, bk1, z, 0, 0, 0);
                s[t] = z;
            }
        }
        // ---- scale + causal mask + row max
        float p[4][4];
        float cm[4] = {-1e30f, -1e30f, -1e30f, -1e30f};
        #pragma unroll
        for (int t = 0; t < 4; ++t)
            #pragma unroll
            for (int r = 0; r < 4; ++r) {
                float sv = (t < ntiles) ? s[t][r] * 0.125f : -1e30f;
                if (c == qt && t == w && l15 > quad * 4 + r) sv = -1e30f;
                p[t][r] = sv;
                cm[r] = fmaxf(cm[r], sv);
            }
        #pragma unroll
        for (int r = 0; r < 4; ++r) {
            float v = cm[r];
            v = fmaxf(v, __shfl_xor(v, 1));
            v = fmaxf(v, __shfl_xor(v, 2));
            v = fmaxf(v, __shfl_xor(v, 4));
            v = fmaxf(v, __shfl_xor(v, 8));
            const float nm = fmaxf(mr[r], v);
            const float a  = __expf(mr[r] - nm);
            mr[r] = nm;
            O[0][r] *= a; O[1][r] *= a; O[2][r] *= a; O[3][r] *= a;
            lr[r] *= a;
        }
        // ---- exp + row sum + P->LDS (bf16)
        float psum[4] = {0.f, 0.f, 0.f, 0.f};
        #pragma unroll
        for (int t = 0; t < 4; ++t) {
            if (t < ntiles) {
                #pragma unroll
                for (int r = 0; r < 4; ++r) {
                    float pv = __expf(p[t][r] - mr[r]);
                    psum[r] += pv;
                    Plds[w][quad * 4 + r][t * 16 + l15] = f2b(pv);
                }
            } else if (t < nhalf * 2) {   // zero stale keys inside PV range
                #pragma unroll
                for (int r = 0; r < 4; ++r)
                    Plds[w][quad * 4 + r][t * 16 + l15] = 0;
            }
        }
        #pragma unroll
        for (int r = 0; r < 4; ++r) {
            float v = psum[r];
            v += __shfl_xor(v, 1);
            v += __shfl_xor(v, 2);
            v += __shfl_xor(v, 4);
            v += __shfl_xor(v, 8);
            lr[r] += v;
        }
        // ---- PV: O += P(16x64) . V_chunk(64x64), B-frags from Vt rows
        short8 pa0 = *(const short8*)&Plds[w][l15][quad * 8];
        short8 pa1 = *(const short8*)&Plds[w][l15][32 + quad * 8];
        #pragma unroll
        for (int ti = 0; ti < 4; ++ti) {
            const u16* vp = vtb + ((size_t)(ti * 16 + l15)) * SEQ + c * 64 + quad * 8;
            short8 bv0 = *(const short8*)vp;
            O[ti] = __builtin_amdgcn_mfma_f32_16x16x32_bf16(pa0, bv0, O[ti], 0, 0, 0);
            if (nhalf == 2) {
                short8 bv1 = *(const short8*)(vp + 32);
                O[ti] = __builtin_amdgcn_mfma_f32_16x16x32_bf16(pa1, bv1, O[ti], 0, 0, 0);
            }
        }
    }
    // ---- epilogue: O/l -> aout[B][T][D_MODEL] bf16
    const int b = bh >> 4, h = bh & 15;
    #pragma unroll
    for (int r = 0; r < 4; ++r) {
        const int trow = qt * 64 + w * 16 + quad * 4 + r;
        const float inv = 1.f / lr[r];
        u16* op = o + ((size_t)(b * SEQ + trow)) * D_MODEL + h * 64 + l15;
        op[0]  = f2b(O[0][r] * inv);
        op[16] = f2b(O[1][r] * inv);
        op[32] = f2b(O[2][r] * inv);
        op[48] = f2b(O[3][r] * inv);
    }
}

// ---------------------------------------------------------------- launch
extern "C" void kernel_launch(void* const* d_in, const int* in_sizes, int n_in,
                              void* d_out, int out_size, void* d_ws, size_t ws_size,
                              hipStream_t stream) {
    const float* x      = (const float*)d_in[0];
    const float* w_qkv  = (const float*)d_in[1];
    const float* w_proj = (const float*)d_in[2];
    const float* b_proj = (const float*)d_in[3];
    float* out = (float*)d_out;

    u16* xb      = (u16*)d_ws;                                 // [8192][1024]
    u16* wt_qkv  = xb + (size_t)ROWS * D_MODEL;                // [3072][1024]
    u16* wt_proj = wt_qkv + (size_t)D_MODEL * K3;              // [1024][1024]
    u16* qws     = wt_proj + (size_t)D_MODEL * D_MODEL;        // [BH][T][64]
    u16* kws     = qws + (size_t)ROWS * D_MODEL;               // [BH][T][64]
    u16* vws     = kws + (size_t)ROWS * D_MODEL;               // [BH][64][T]
    u16* aout    = vws + (size_t)ROWS * D_MODEL;               // [8192][1024]

    conv_f2b<<<(ROWS * D_MODEL + 255) / 256, 256, 0, stream>>>(x, xb, ROWS * D_MODEL);
    transpose_f2b<<<(D_MODEL * K3 + 255) / 256, 256, 0, stream>>>(w_qkv, wt_qkv, D_MODEL, K3);
    transpose_f2b<<<(D_MODEL * D_MODEL + 255) / 256, 256, 0, stream>>>(w_proj, wt_proj, D_MODEL, D_MODEL);

    gemm_qkv<<<dim3(K3 / 64, ROWS / 64), 256, 0, stream>>>(xb, wt_qkv, qws, kws, vws);

    attn_mfma<<<dim3(SEQ / 64, BATCH * N_HEADS), 256, 0, stream>>>(qws, kws, vws, aout);

    gemm_proj<<<dim3(D_MODEL / 64, ROWS / 64), 256, 0, stream>>>(aout, wt_proj, b_proj, out);
}

// Round 4
// 484.240 us; speedup vs baseline: 6.5275x; 1.4404x over previous
//
#include <hip/hip_runtime.h>
#include <stdint.h>

#define D_MODEL 1024
#define N_HEADS 16
#define HEAD_DIM 64
#define BATCH 4
#define SEQ 2048
#define ROWS (BATCH * SEQ)   /* 8192 */
#define K3 (3 * D_MODEL)     /* 3072 */
#define NQT (SEQ / 64)       /* 32 q-tiles of 64 */

typedef unsigned short u16;
typedef __attribute__((ext_vector_type(8))) short short8;
typedef __attribute__((ext_vector_type(4))) float floatx4;

__device__ __forceinline__ float bf2f(u16 u) {
    return __uint_as_float(((unsigned)u) << 16);
}
__device__ __forceinline__ u16 f2b(float f) {
    unsigned u = __float_as_uint(f);
    u = u + 0x7fffu + ((u >> 16) & 1u);   // RNE
    return (u16)(u >> 16);
}
__device__ __forceinline__ unsigned pk2(float a, float b) {
    return (unsigned)f2b(a) | ((unsigned)f2b(b) << 16);
}

// -------------------------------------------------- fp32 -> bf16 conversions
__global__ __launch_bounds__(256) void conv_f2b(const float* __restrict__ x,
                                                u16* __restrict__ xb, int n) {
    int i = blockIdx.x * 256 + threadIdx.x;
    if (i < n) xb[i] = f2b(x[i]);
}

__global__ __launch_bounds__(256) void transpose_f2b(const float* __restrict__ w,
                                                     u16* __restrict__ wt,
                                                     int R, int C) {
    int idx = blockIdx.x * 256 + threadIdx.x;
    if (idx >= R * C) return;
    int r = idx / C, c = idx - r * C;
    wt[(size_t)c * R + r] = f2b(w[idx]);
}

// ---------------------------------------------------------------- GEMM core
// 64x64 tile, 4 waves 2x2, BK=64, 16x16x32 bf16 (unchanged, passing).
#define GEMM_CORE(KDIM)                                                        \
    __shared__ u16 As[64][72];                                                 \
    __shared__ u16 Bs[64][72];                                                 \
    const int tid  = threadIdx.x;                                              \
    const int wave = tid >> 6, lane = tid & 63;                                \
    const int wr = wave >> 1, wc = wave & 1;                                   \
    const int m0 = blockIdx.y * 64, n0 = blockIdx.x * 64;                      \
    const int lr = tid >> 2, lc = (tid & 3) * 16;                              \
    const u16* Ap = A + (size_t)(m0 + lr) * (KDIM) + lc;                       \
    const u16* Bp = Bt + (size_t)(n0 + lr) * (KDIM) + lc;                      \
    floatx4 acc[2][2] = {};                                                    \
    for (int k0 = 0; k0 < (KDIM); k0 += 64) {                                  \
        uint4 a0 = *(const uint4*)(Ap + k0);                                   \
        uint4 a1 = *(const uint4*)(Ap + k0 + 8);                               \
        uint4 b0 = *(const uint4*)(Bp + k0);                                   \
        uint4 b1 = *(const uint4*)(Bp + k0 + 8);                               \
        __syncthreads();                                                       \
        *(uint4*)&As[lr][lc]     = a0;                                         \
        *(uint4*)&As[lr][lc + 8] = a1;                                         \
        *(uint4*)&Bs[lr][lc]     = b0;                                         \
        *(uint4*)&Bs[lr][lc + 8] = b1;                                         \
        __syncthreads();                                                       \
        _Pragma("unroll")                                                      \
        for (int ks = 0; ks < 2; ++ks) {                                       \
            const int kk = ks * 32 + (lane >> 4) * 8;                          \
            short8 af0 = *(const short8*)&As[wr * 32 + (lane & 15)][kk];       \
            short8 af1 = *(const short8*)&As[wr * 32 + 16 + (lane & 15)][kk];  \
            short8 bf0 = *(const short8*)&Bs[wc * 32 + (lane & 15)][kk];       \
            short8 bf1 = *(const short8*)&Bs[wc * 32 + 16 + (lane & 15)][kk];  \
            acc[0][0] = __builtin_amdgcn_mfma_f32_16x16x32_bf16(af0, bf0, acc[0][0], 0, 0, 0); \
            acc[0][1] = __builtin_amdgcn_mfma_f32_16x16x32_bf16(af0, bf1, acc[0][1], 0, 0, 0); \
            acc[1][0] = __builtin_amdgcn_mfma_f32_16x16x32_bf16(af1, bf0, acc[1][0], 0, 0, 0); \
            acc[1][1] = __builtin_amdgcn_mfma_f32_16x16x32_bf16(af1, bf1, acc[1][1], 0, 0, 0); \
        }                                                                      \
    }

// GEMM1: xb @ wqkv -> q,k as [BH][T][64]; v TRANSPOSED as [BH][64][T]
__global__ __launch_bounds__(256) void gemm_qkv(const u16* __restrict__ A,
                                                const u16* __restrict__ Bt,
                                                u16* __restrict__ qo,
                                                u16* __restrict__ ko,
                                                u16* __restrict__ vo) {
    GEMM_CORE(D_MODEL)
    #pragma unroll
    for (int i = 0; i < 2; ++i)
        #pragma unroll
        for (int j = 0; j < 2; ++j) {
            const int col   = n0 + wc * 32 + j * 16 + (lane & 15);
            const int rb    = m0 + wr * 32 + i * 16 + (lane >> 4) * 4;
            const int which = col >> 10;
            const int cc    = col & 1023;
            const int h = cc >> 6, d = cc & 63;
            #pragma unroll
            for (int rr = 0; rr < 4; ++rr) {
                const int row = rb + rr;
                const int b = row >> 11, t = row & 2047;
                const u16 val = f2b(acc[i][j][rr]);
                if (which == 0)
                    qo[(((size_t)(b * N_HEADS + h)) * SEQ + t) * HEAD_DIM + d] = val;
                else if (which == 1)
                    ko[(((size_t)(b * N_HEADS + h)) * SEQ + t) * HEAD_DIM + d] = val;
                else
                    vo[(((size_t)(b * N_HEADS + h)) * HEAD_DIM + d) * SEQ + t] = val;
            }
        }
}

// GEMM2: attn_out[8192][1024] @ wproj + bias -> d_out fp32
__global__ __launch_bounds__(256) void gemm_proj(const u16* __restrict__ A,
                                                 const u16* __restrict__ Bt,
                                                 const float* __restrict__ bias,
                                                 float* __restrict__ out) {
    GEMM_CORE(D_MODEL)
    #pragma unroll
    for (int i = 0; i < 2; ++i)
        #pragma unroll
        for (int j = 0; j < 2; ++j) {
            const int col = n0 + wc * 32 + j * 16 + (lane & 15);
            const int rb  = m0 + wr * 32 + i * 16 + (lane >> 4) * 4;
            const float bv = bias[col];
            #pragma unroll
            for (int rr = 0; rr < 4; ++rr) {
                const int row = rb + rr;
                out[(size_t)row * D_MODEL + col] = acc[i][j][rr] + bv;
            }
        }
}

// ------------------------------------------------------- MFMA flash attention
// S^T formulation: S^T = K.Q^T  (A=K-tile, B=Q-tile) -> lane l15 = QUERY,
// (quad,reg) = key. Per-lane softmax state (one query per lane): row max/sum
// = local reduce + shfl_xor(16)/shfl_xor(32). P stored to per-wave LDS as
// packed b64 rows P[q][key]; PV reads it back as the B-frag of
// O^T = Vt . P^T (contiguous 16B). Work balance: block = q-tile pair
// (NQT-1-p, p) -> uniform ~33 chunks/block; grid (16, 64).
__global__ __launch_bounds__(256) void attn_mfma(const u16* __restrict__ q,
                                                 const u16* __restrict__ k,
                                                 const u16* __restrict__ vt,
                                                 u16* __restrict__ o) {
    __shared__ u16 Plds[4][16][72];
    const int tid = threadIdx.x;
    const int w = tid >> 6, lane = tid & 63;
    const int quad = lane >> 4, l15 = lane & 15;
    const int bh = blockIdx.y;
    const int b = bh >> 4, h = bh & 15;
    const u16* kb  = k  + (size_t)bh * SEQ * HEAD_DIM;
    const u16* vtb = vt + (size_t)bh * HEAD_DIM * SEQ;

    #pragma unroll 1
    for (int seg = 0; seg < 2; ++seg) {
        const int qt = seg ? (int)blockIdx.x : (NQT - 1 - (int)blockIdx.x);
        const int qrow = qt * 64 + w * 16 + l15;
        const u16* qp = q + ((size_t)bh * SEQ + qrow) * HEAD_DIM + quad * 8;
        const short8 bq0 = *(const short8*)(qp);
        const short8 bq1 = *(const short8*)(qp + 32);

        floatx4 O[4] = {};
        float m = -1e30f, l = 0.f;

        for (int c = 0; c <= qt; ++c) {
            const int ntiles = (c == qt) ? (w + 1) : 4;   // wave-uniform
            const int nhalf  = (ntiles + 1) >> 1;
            // ---- S^T tiles: D[key_local][query]
            floatx4 s[4];
            #pragma unroll
            for (int kt = 0; kt < 4; ++kt) {
                floatx4 z = {};
                if (kt < ntiles) {
                    const u16* kp = kb + ((size_t)(c * 64 + kt * 16 + l15)) * HEAD_DIM + quad * 8;
                    short8 ak0 = *(const short8*)kp;
                    short8 ak1 = *(const short8*)(kp + 32);
                    z = __builtin_amdgcn_mfma_f32_16x16x32_bf16(ak0, bq0, z, 0, 0, 0);
                    z = __builtin_amdgcn_mfma_f32_16x16x32_bf16(ak1, bq1, z, 0, 0, 0);
                }
                s[kt] = z;
            }
            // ---- scale + causal mask + per-lane (one query) max
            float p[4][4];
            float cm = -1e30f;
            #pragma unroll
            for (int kt = 0; kt < 4; ++kt)
                #pragma unroll
                for (int r = 0; r < 4; ++r) {
                    float sv = s[kt][r] * 0.125f;
                    const bool valid = (kt < ntiles) &&
                        !(c == qt && kt == w && quad * 4 + r > l15);
                    sv = valid ? sv : -1e30f;
                    p[kt][r] = sv;
                    cm = fmaxf(cm, sv);
                }
            cm = fmaxf(cm, __shfl_xor(cm, 16));
            cm = fmaxf(cm, __shfl_xor(cm, 32));
            const float nm    = fmaxf(m, cm);
            const float alpha = __expf(m - nm);
            m = nm;
            // ---- exp + local sum + P->LDS (packed b64)
            float ls = 0.f;
            #pragma unroll
            for (int kt = 0; kt < 4; ++kt) {
                if (kt < ntiles) {
                    float p0 = __expf(p[kt][0] - nm);
                    float p1 = __expf(p[kt][1] - nm);
                    float p2 = __expf(p[kt][2] - nm);
                    float p3 = __expf(p[kt][3] - nm);
                    ls += (p0 + p1) + (p2 + p3);
                    uint2 pkv;
                    pkv.x = pk2(p0, p1);
                    pkv.y = pk2(p2, p3);
                    *(uint2*)&Plds[w][l15][kt * 16 + quad * 4] = pkv;
                } else if (kt < nhalf * 2) {
                    uint2 z2; z2.x = 0; z2.y = 0;
                    *(uint2*)&Plds[w][l15][kt * 16 + quad * 4] = z2;
                }
            }
            ls += __shfl_xor(ls, 16);
            ls += __shfl_xor(ls, 32);
            l = l * alpha + ls;
            // ---- rescale O, then PV: O^T += Vt . P^T
            #pragma unroll
            for (int dt = 0; dt < 4; ++dt) {
                O[dt][0] *= alpha; O[dt][1] *= alpha;
                O[dt][2] *= alpha; O[dt][3] *= alpha;
            }
            short8 pb0 = *(const short8*)&Plds[w][l15][quad * 8];
            #pragma unroll
            for (int dt = 0; dt < 4; ++dt) {
                const u16* vp = vtb + ((size_t)(dt * 16 + l15)) * SEQ + c * 64 + quad * 8;
                short8 av0 = *(const short8*)vp;
                O[dt] = __builtin_amdgcn_mfma_f32_16x16x32_bf16(av0, pb0, O[dt], 0, 0, 0);
            }
            if (nhalf == 2) {
                short8 pb1 = *(const short8*)&Plds[w][l15][32 + quad * 8];
                #pragma unroll
                for (int dt = 0; dt < 4; ++dt) {
                    const u16* vp = vtb + ((size_t)(dt * 16 + l15)) * SEQ + c * 64 + 32 + quad * 8;
                    short8 av1 = *(const short8*)vp;
                    O[dt] = __builtin_amdgcn_mfma_f32_16x16x32_bf16(av1, pb1, O[dt], 0, 0, 0);
                }
            }
        }
        // ---- epilogue: lane owns query qrow; regs = d = dt*16+quad*4+r
        const float inv = 1.f / l;
        u16* op = o + ((size_t)(b * SEQ + qrow)) * D_MODEL + h * 64 + quad * 4;
        #pragma unroll
        for (int dt = 0; dt < 4; ++dt) {
            uint2 pkv;
            pkv.x = pk2(O[dt][0] * inv, O[dt][1] * inv);
            pkv.y = pk2(O[dt][2] * inv, O[dt][3] * inv);
            *(uint2*)(op + dt * 16) = pkv;
        }
    }
}

// ---------------------------------------------------------------- launch
extern "C" void kernel_launch(void* const* d_in, const int* in_sizes, int n_in,
                              void* d_out, int out_size, void* d_ws, size_t ws_size,
                              hipStream_t stream) {
    const float* x      = (const float*)d_in[0];
    const float* w_qkv  = (const float*)d_in[1];
    const float* w_proj = (const float*)d_in[2];
    const float* b_proj = (const float*)d_in[3];
    float* out = (float*)d_out;

    u16* xb      = (u16*)d_ws;                                 // [8192][1024]
    u16* wt_qkv  = xb + (size_t)ROWS * D_MODEL;                // [3072][1024]
    u16* wt_proj = wt_qkv + (size_t)D_MODEL * K3;              // [1024][1024]
    u16* qws     = wt_proj + (size_t)D_MODEL * D_MODEL;        // [BH][T][64]
    u16* kws     = qws + (size_t)ROWS * D_MODEL;               // [BH][T][64]
    u16* vws     = kws + (size_t)ROWS * D_MODEL;               // [BH][64][T]
    u16* aout    = vws + (size_t)ROWS * D_MODEL;               // [8192][1024]

    conv_f2b<<<(ROWS * D_MODEL + 255) / 256, 256, 0, stream>>>(x, xb, ROWS * D_MODEL);
    transpose_f2b<<<(D_MODEL * K3 + 255) / 256, 256, 0, stream>>>(w_qkv, wt_qkv, D_MODEL, K3);
    transpose_f2b<<<(D_MODEL * D_MODEL + 255) / 256, 256, 0, stream>>>(w_proj, wt_proj, D_MODEL, D_MODEL);

    gemm_qkv<<<dim3(K3 / 64, ROWS / 64), 256, 0, stream>>>(xb, wt_qkv, qws, kws, vws);

    attn_mfma<<<dim3(NQT / 2, BATCH * N_HEADS), 256, 0, stream>>>(qws, kws, vws, aout);

    gemm_proj<<<dim3(D_MODEL / 64, ROWS / 64), 256, 0, stream>>>(aout, wt_proj, b_proj, out);
}